// Round 15
// baseline (2060.666 us; speedup 1.0000x reference)
//
#include <hip/hip_runtime.h>

#define EMB   300
#define EMB2  600
#define NLAYERS 5
#define NN    100000
#define NE    400000
#define NG    1024
#define BN_EPS 1e-5f
#define MPAD  100352            // 256-mult padding for M-tile overreads
#define NB_SC 391               // ceil(NN/256)
#define HLD   304               // h row stride (bf16): 300 real + 4 pad

// h   : [NN][304] bf16, RAW (pre-BN) layer output; BN applied on read.
// aggS: [MPAD][320] bf16 hi-only (300 real + 20 zero cols)
// h1S : [CHUNK][608] bf16 (600 real + 8 zero)
// B1n : [L][640 n][640 k]  : k [0,320)=W1h (kk<300 real), [320,640)=W1l
// B2n : [L][384 n][1280 k] : k [0,640)=W2h (kk<600 real), [640,1280)=W2l
// All A K-windows are 64-aligned; A overreads pair with ZERO B rows.
// stats: sum at [0,384), sumsq at [384,768)

typedef __bf16 bf16;
typedef __attribute__((ext_vector_type(4))) __bf16 bf16x4;
typedef __attribute__((ext_vector_type(8))) __bf16 bf16x8;
typedef __attribute__((ext_vector_type(4))) float f32x4;

typedef __attribute__((address_space(3))) unsigned int lds_uint;
typedef __attribute__((address_space(1))) const unsigned int gbl_uint;

__device__ __forceinline__ void gld_lds16(const bf16* g, bf16* l) {
  // async 16B/lane HBM->LDS; LDS dest = wave-uniform base + lane*16
  __builtin_amdgcn_global_load_lds((gbl_uint*)g, (lds_uint*)l, 16, 0, 0);
}

// ---------------- CSR build ----------------
__global__ void k_count(const int* __restrict__ dst, int* __restrict__ cnt) {
  int e = blockIdx.x * 256 + threadIdx.x;
  if (e < NE) atomicAdd(&cnt[dst[e]], 1);
}

__global__ void k_bsum(const int* __restrict__ cnt, int* __restrict__ bsum) {
  __shared__ int red[256];
  int i = blockIdx.x * 256 + threadIdx.x;
  red[threadIdx.x] = (i < NN) ? cnt[i] : 0;
  __syncthreads();
  for (int off = 128; off; off >>= 1) {
    if (threadIdx.x < off) red[threadIdx.x] += red[threadIdx.x + off];
    __syncthreads();
  }
  if (!threadIdx.x) bsum[blockIdx.x] = red[0];
}

__global__ void k_bscan(const int* __restrict__ bsum, int* __restrict__ bpre) {
  __shared__ int s[512];
  int t = threadIdx.x;
  s[t] = (t < NB_SC) ? bsum[t] : 0;
  __syncthreads();
  for (int off = 1; off < 512; off <<= 1) {
    int v = (t >= off) ? s[t - off] : 0;
    __syncthreads();
    s[t] += v;
    __syncthreads();
  }
  if (t < NB_SC) bpre[t] = t ? s[t - 1] : 0;
}

__global__ void k_expand(const int* __restrict__ cnt, const int* __restrict__ bpre,
                         int* __restrict__ rowptr, int* __restrict__ cursor) {
  __shared__ int s[256];
  int t = threadIdx.x, i = blockIdx.x * 256 + t;
  int v = (i < NN) ? cnt[i] : 0;
  s[t] = v;
  __syncthreads();
  for (int off = 1; off < 256; off <<= 1) {
    int u = (t >= off) ? s[t - off] : 0;
    __syncthreads();
    s[t] += u;
    __syncthreads();
  }
  int excl = bpre[blockIdx.x] + s[t] - v;
  if (i < NN) { rowptr[i] = excl; cursor[i] = excl; }
  if (i == NN - 1) rowptr[NN] = excl + v;
}

__global__ void k_fill(const int* __restrict__ ei, const int* __restrict__ ea,
                       int* __restrict__ cursor, int* __restrict__ packed) {
  int e = blockIdx.x * 256 + threadIdx.x;
  if (e >= NE) return;
  int d = ei[NE + e];
  int s = ei[e];
  int comb = ea[2 * e] * 3 + ea[2 * e + 1];
  int pos = atomicAdd(&cursor[d], 1);
  packed[pos] = s | (comb << 20);
}

// ---------------- init h (bf16, raw) ----------------
__global__ void k_init(const int* __restrict__ x, const float4* __restrict__ ae1,
                       const float4* __restrict__ ae2, bf16* __restrict__ h) {
  int idx = blockIdx.x * 256 + threadIdx.x;
  if (idx >= NN * 76) return;
  int n = idx / 76, v = idx - n * 76;
  bf16x4 r4;
  if (v < 75) {
    int x0 = x[2 * n], x1 = x[2 * n + 1];
    float4 a = ae1[x0 * 75 + v], b = ae2[x1 * 75 + v];
    r4[0] = (bf16)(a.x + b.x); r4[1] = (bf16)(a.y + b.y);
    r4[2] = (bf16)(a.z + b.z); r4[3] = (bf16)(a.w + b.w);
  } else {
    r4[0] = r4[1] = r4[2] = r4[3] = (bf16)0.f;
  }
  *(bf16x4*)(h + (size_t)n * HLD + 4 * v) = r4;
}

// ---------------- weight/bias prep (split bf16, dup-free, N-major) ----------
__global__ void k_prepw1(const float* __restrict__ W1, bf16* __restrict__ B1n) {
  int idx = blockIdx.x * 256 + threadIdx.x;
  if (idx >= 5 * 640 * 640) return;
  int l = idx / (640 * 640), rem = idx - l * (640 * 640);
  int n = rem / 640, kp = rem - n * 640;
  int lo = kp >= 320;
  int kk = lo ? kp - 320 : kp;
  float w = (n < 600 && kk < 300) ? W1[(size_t)l * 300 * 600 + kk * 600 + n] : 0.f;
  bf16 hi = (bf16)w;
  B1n[idx] = lo ? (bf16)(w - (float)hi) : hi;
}

__global__ void k_prepw2(const float* __restrict__ W2, bf16* __restrict__ B2n) {
  int idx = blockIdx.x * 256 + threadIdx.x;
  if (idx >= 5 * 384 * 1280) return;
  int l = idx / (384 * 1280), rem = idx - l * (384 * 1280);
  int n = rem / 1280, kp = rem - n * 1280;
  int lo = kp >= 640;
  int kk = lo ? kp - 640 : kp;
  float w = (n < 300 && kk < 600) ? W2[(size_t)l * 600 * 300 + kk * 300 + n] : 0.f;
  bf16 hi = (bf16)w;
  B2n[idx] = lo ? (bf16)(w - (float)hi) : hi;
}

__global__ void k_prepb(const float* __restrict__ b1, const float* __restrict__ b2,
                        float* __restrict__ b1p, float* __restrict__ b2p) {
  int idx = blockIdx.x * 256 + threadIdx.x;
  if (idx < 5 * 640) {
    int l = idx / 640, n = idx - l * 640;
    b1p[idx] = (n < 600) ? b1[l * 600 + n] : 0.f;
  } else if (idx < 5 * 640 + 5 * 384) {
    int j = idx - 5 * 640;
    int l = j / 384, n = j - l * 384;
    b2p[j] = (n < 300) ? b2[l * 300 + n] : 0.f;
  }
}

// ---------------- aggregation (wave per node, bf16x8 vector gather) -----------
// r11 version (proven best).
template <int APPLY>
__global__ __launch_bounds__(256) void k_agg(
    const bf16* __restrict__ h, const int* __restrict__ rowptr,
    const int* __restrict__ packed, const float* __restrict__ be1,
    const float* __restrict__ be2, const float* __restrict__ coef,
    bf16* __restrict__ aggS) {
  __shared__ float tab[9 * HLD];            // 304-padded rows; cols >=300 zero
  for (int i = threadIdx.x; i < 9 * HLD; i += 256) {
    int cc = i / HLD, d = i - cc * HLD;
    tab[i] = (d < EMB)
                 ? be1[(cc / 3) * EMB + d] + be2[(cc - (cc / 3) * 3) * EMB + d]
                 : 0.f;
  }
  __syncthreads();
  const int ty = threadIdx.x >> 6, lane = threadIdx.x & 63;
  const int n = blockIdx.x * 4 + ty;
  const int c = 8 * lane;                   // this lane's chunk base col
  const bool act = lane < 38;               // chunks 0..37 = cols 0..303

  float a8[8], b8[8], acc[8];
  if (act) {
#pragma unroll
    for (int j = 0; j < 8; j++) {
      int d = c + j;
      a8[j] = APPLY ? coef[d] : 1.f;
      b8[j] = APPLY ? coef[HLD + d] : 0.f;
    }
    const bf16* hn = h + (size_t)n * HLD;
#pragma unroll
    for (int j = 0; j < 8; j++) {
      int d = c + j;
      float hv = (float)hn[d];
      if (APPLY) hv = fmaxf(fmaf(a8[j], hv, b8[j]), 0.f);
      acc[j] = hv + be1[4 * EMB + d] + be2[d];
    }
  }
  int e0 = rowptr[n], e1 = rowptr[n + 1];
  for (int e = e0; e < e1; ++e) {
    int pk = packed[e];
    const bf16* hr = h + (size_t)(pk & 0xFFFFF) * HLD;
    const float* tr = tab + (pk >> 20) * HLD;
    if (act) {
      bf16x8 v = *(const bf16x8*)(hr + c);
      f32x4 t0 = *(const f32x4*)(tr + c);
      f32x4 t1 = *(const f32x4*)(tr + c + 4);
#pragma unroll
      for (int j = 0; j < 8; j++) {
        float hv = (float)v[j];
        if (APPLY) hv = fmaxf(fmaf(a8[j], hv, b8[j]), 0.f);
        acc[j] += hv + (j < 4 ? t0[j] : t1[j - 4]);
      }
    }
  }
  bf16* row = aggS + (size_t)n * 320;
  if (lane < 40) {                          // chunks 38,39 = pad cols 304..319
    bf16x8 o;
#pragma unroll
    for (int j = 0; j < 8; j++)
      o[j] = (act && c + j < EMB) ? (bf16)acc[j] : (bf16)0.f;
    *(bf16x8*)(row + c) = o;
  }
}

// ---------------- MFMA GEMM (256x128, dual-section, 2-phase COUNTED vmcnt) ----
// 512 threads = 8 waves (4 wr x 2 wc), per-wave output 64x64.
// T4 recipe (m218/m139): double-buffered LDS (128 KB) + raw s_barrier +
// COUNTED s_waitcnt vmcnt(8) — each wave issues exactly 8 global_load_lds per
// stage, so vmcnt(8) retires the CURRENT buffer's loads while the prefetched
// next-buffer 8 stay in flight across the barrier (no vmcnt(0) drain in the
// main loop). Safety: barrier-1 after per-wave vmcnt(8) => cur buffer fully
// landed for all waves; barrier-2 after compute => all ds_reads consumed
// before anyone re-stages into that buffer. Last iter drains vmcnt(0).
// Per-accumulator MFMA K-order unchanged -> numerically identical to r11/r14.
// XOR bank-swizzle via PRE-SWIZZLED global source chunk (l&7)^(l>>3).
// MODE 1: C = h1S (ld 608): relu, write gcol<608.
// MODE 2: C = h raw bf16 (ld 304), gcol<304 && grow<row_limit; fused BN stats.
template <int K_SECT, int LDA, int LDB, int B_LO, int MODE, int NTILE>
__global__ __launch_bounds__(512) void k_mfma(
    const bf16* __restrict__ A,
    const bf16* __restrict__ Bn,
    const float* __restrict__ bias,
    bf16* __restrict__ C, float* __restrict__ stats, int row_limit) {
  __shared__ __align__(16) bf16 As[2][256 * 64];
  __shared__ __align__(16) bf16 Bs0[2][128 * 64];
  __shared__ __align__(16) bf16 Bs1[2][128 * 64];
  const int t = threadIdx.x, lane = t & 63, wid = t >> 6;
  const int wr = wid >> 1, wc = wid & 1;

  // bijective XCD swizzle (m204)
  const int nwg = (int)gridDim.x;
  const int q = nwg >> 3, r = nwg & 7;
  const int xcd = blockIdx.x & 7, slot = blockIdx.x >> 3;
  const int lin = (xcd < r ? xcd * (q + 1) : r * (q + 1) + (xcd - r) * q) + slot;
  const int row0 = (lin / NTILE) * 256, n0 = (lin % NTILE) * 128;

  // per-lane pre-swizzled source chunk + row-within-instruction
  const int csw = (lane & 7) ^ (lane >> 3);       // global 8-elem chunk index
  const int r8  = lane >> 3;                       // row within 8-row inst

  auto stage = [&](int kt, int buf) {              // 8 gld_lds per wave
    int kbase = kt * 64;
    const bf16* ga = A  + (size_t)(row0 + wid * 32 + r8) * LDA + kbase + csw * 8;
    const bf16* gb = Bn + (size_t)(n0  + wid * 16 + r8) * LDB + kbase + csw * 8;
#pragma unroll
    for (int i = 0; i < 4; i++)
      gld_lds16(ga + (size_t)(i * 8) * LDA, &As[buf][(wid * 32 + i * 8) * 64]);
#pragma unroll
    for (int i = 0; i < 2; i++) {
      gld_lds16(gb + (size_t)(i * 8) * LDB,        &Bs0[buf][(wid * 16 + i * 8) * 64]);
      gld_lds16(gb + (size_t)(i * 8) * LDB + B_LO, &Bs1[buf][(wid * 16 + i * 8) * 64]);
    }
  };

  f32x4 acc[4][4] = {};
  stage(0, 0);
  int cur = 0;
  for (int kt = 0; kt < K_SECT; kt++) {
    if (kt + 1 < K_SECT) {
      stage(kt + 1, cur ^ 1);                       // prefetch next window
      asm volatile("s_waitcnt vmcnt(8)" ::: "memory");   // cur landed; next in flight
    } else {
      asm volatile("s_waitcnt vmcnt(0)" ::: "memory");   // final drain
    }
    __builtin_amdgcn_s_barrier();                   // all waves: cur visible
#pragma unroll
    for (int kk = 0; kk < 2; kk++) {
      bf16x8 af[4], b0[4], b1[4];
#pragma unroll
      for (int mf = 0; mf < 4; mf++) {
        int rr = wr * 64 + mf * 16 + (lane & 15);
        int cc = (kk * 4 + (lane >> 4)) ^ (rr & 7);
        af[mf] = *(const bf16x8*)((const char*)&As[cur][0] + rr * 128 + (cc << 4));
      }
#pragma unroll
      for (int nf = 0; nf < 4; nf++) {
        int n = wc * 64 + nf * 16 + (lane & 15);
        int cc = (kk * 4 + (lane >> 4)) ^ (n & 7);
        b0[nf] = *(const bf16x8*)((const char*)&Bs0[cur][0] + n * 128 + (cc << 4));
        b1[nf] = *(const bf16x8*)((const char*)&Bs1[cur][0] + n * 128 + (cc << 4));
      }
#pragma unroll
      for (int mf = 0; mf < 4; mf++)
#pragma unroll
        for (int nf = 0; nf < 4; nf++) {
          acc[mf][nf] = __builtin_amdgcn_mfma_f32_16x16x32_bf16(
              af[mf], b0[nf], acc[mf][nf], 0, 0, 0);
          acc[mf][nf] = __builtin_amdgcn_mfma_f32_16x16x32_bf16(
              af[mf], b1[nf], acc[mf][nf], 0, 0, 0);
        }
    }
    __builtin_amdgcn_s_barrier();                   // reads done before re-stage
    cur ^= 1;
  }

  const int rq = (lane >> 4) << 2;   // 0,4,8,12
  const int cl = lane & 15;
#pragma unroll
  for (int nf = 0; nf < 4; nf++) {
    const int gcol = n0 + wc * 64 + nf * 16 + cl;
    float s = 0.f, qq = 0.f;
#pragma unroll
    for (int mf = 0; mf < 4; mf++)
#pragma unroll
      for (int rr = 0; rr < 4; rr++) {
        int grow = row0 + wr * 64 + mf * 16 + rq + rr;
        float v = acc[mf][nf][rr] + bias[gcol];
        if (MODE == 1) {
          if (gcol < 608) C[(size_t)grow * 608 + gcol] = (bf16)fmaxf(v, 0.f);
        } else {
          if (grow < row_limit) {
            if (gcol < HLD) C[(size_t)grow * HLD + gcol] = (bf16)v;
            s += v; qq += v * v;
          }
        }
      }
    if (MODE == 2) {
      s  += __shfl_down(s, 32);  s  += __shfl_down(s, 16);
      qq += __shfl_down(qq, 32); qq += __shfl_down(qq, 16);
      if (lane < 16 && gcol < EMB) {
        atomicAdd(&stats[gcol], s);
        atomicAdd(&stats[384 + gcol], qq);
      }
    }
  }
}

// ---------------- BN coef from fused stats ----------------
__global__ void k_bnfinal(const float* __restrict__ stats, const float* __restrict__ sc,
                          const float* __restrict__ bi, float* __restrict__ coef) {
  int c = threadIdx.x;
  if (c >= HLD) return;
  if (c < EMB) {
    float mean = stats[c] * (1.0f / NN);
    float var  = stats[384 + c] * (1.0f / NN) - mean * mean;
    float inv  = rsqrtf(var + BN_EPS);
    float a = inv * sc[c];
    coef[c] = a;
    coef[HLD + c] = bi[c] - mean * a;
  } else {
    coef[c] = 0.f;
    coef[HLD + c] = 0.f;
  }
}

// ---------------- pooling (applies final layer's BN, no relu) ----------------
__device__ __forceinline__ int lowerb(const int* a, int n, int v) {
  int lo = 0, hi = n;
  while (lo < hi) { int mid = (lo + hi) >> 1; if (a[mid] < v) lo = mid + 1; else hi = mid; }
  return lo;
}

__global__ void k_pool(const bf16* __restrict__ h, const int* __restrict__ batch,
                       const float* __restrict__ coef, float* __restrict__ pooled) {
  int g = blockIdx.x;
  __shared__ int se[2];
  if (threadIdx.x == 0) { se[0] = lowerb(batch, NN, g); se[1] = lowerb(batch, NN, g + 1); }
  __syncthreads();
  int start = se[0], end = se[1];
  for (int c = threadIdx.x; c < EMB; c += 256) {
    float s = 0.f;
    for (int r = start; r < end; ++r) s += (float)h[(size_t)r * HLD + c];
    float outv = 0.f;
    if (end > start) {
      float m = s / (float)(end - start);
      outv = fmaf(coef[c], m, coef[HLD + c]);
    }
    pooled[(size_t)g * EMB + c] = outv;
  }
}

// ---------------- projection head ----------------
template <bool RELU>
__global__ void k_rowgemm(const float* __restrict__ X, const float* __restrict__ W,
                          const float* __restrict__ bias, float* __restrict__ Y) {
  int g = blockIdx.x;
  __shared__ float row[EMB];
  for (int i = threadIdx.x; i < EMB; i += 256) row[i] = X[(size_t)g * EMB + i];
  __syncthreads();
  for (int c = threadIdx.x; c < EMB; c += 256) {
    float acc = bias[c];
    for (int k = 0; k < EMB; k++) acc += row[k] * W[(size_t)k * EMB + c];
    if (RELU) acc = fmaxf(acc, 0.f);
    Y[(size_t)g * EMB + c] = acc;
  }
}

__global__ void k_norm(float* __restrict__ p) {
  int g = blockIdx.x;
  __shared__ float red[256];
  float s = 0.f;
  for (int c = threadIdx.x; c < EMB; c += 256) { float v = p[(size_t)g * EMB + c]; s += v * v; }
  red[threadIdx.x] = s; __syncthreads();
  for (int off = 128; off > 0; off >>= 1) {
    if (threadIdx.x < off) red[threadIdx.x] += red[threadIdx.x + off];
    __syncthreads();
  }
  float inv = 1.0f / fmaxf(sqrtf(red[0]), 1e-12f);
  for (int c = threadIdx.x; c < EMB; c += 256) p[(size_t)g * EMB + c] *= inv;
}

__global__ __launch_bounds__(256) void k_logits(const float* __restrict__ feats,
                                                float* __restrict__ out) {
  __shared__ float SA[16 * EMB];
  __shared__ float SB[16 * EMB];
  int t = threadIdx.y * 16 + threadIdx.x;
  int i0 = blockIdx.y * 16, j0 = blockIdx.x * 16;
  for (int idx = t; idx < 16 * EMB; idx += 256) {
    int r = idx / EMB, c = idx - r * EMB;
    SA[idx] = feats[(size_t)(i0 + r) * EMB + c];
    SB[idx] = feats[(size_t)(512 + j0 + r) * EMB + c];
  }
  __syncthreads();
  float acc = 0.f;
  const float* a = &SA[threadIdx.y * EMB];
  const float* b = &SB[threadIdx.x * EMB];
  for (int k = 0; k < EMB; k++) acc += a[k] * b[k];
  out[(size_t)(i0 + threadIdx.y) * 512 + j0 + threadIdx.x] = acc / 0.04f;
}

// ---------------- host ----------------
extern "C" void kernel_launch(void* const* d_in, const int* in_sizes, int n_in,
                              void* d_out, int out_size, void* d_ws, size_t ws_size,
                              hipStream_t stream) {
  const int*   x         = (const int*)d_in[0];
  const int*   ei        = (const int*)d_in[1];
  const int*   ea        = (const int*)d_in[2];
  const int*   batch     = (const int*)d_in[3];
  const float* atom_emb1 = (const float*)d_in[4];
  const float* atom_emb2 = (const float*)d_in[5];
  const float* bond_emb1 = (const float*)d_in[6];
  const float* bond_emb2 = (const float*)d_in[7];
  const float* W1        = (const float*)d_in[8];
  const float* b1        = (const float*)d_in[9];
  const float* W2        = (const float*)d_in[10];
  const float* b2        = (const float*)d_in[11];
  const float* bn_scale  = (const float*)d_in[12];
  const float* bn_bias   = (const float*)d_in[13];
  const float* pW1       = (const float*)d_in[14];
  const float* pb1       = (const float*)d_in[15];
  const float* pW2       = (const float*)d_in[16];
  const float* pb2       = (const float*)d_in[17];
  float* out = (float*)d_out;

  char* w = (char*)d_ws;
  size_t used = 0;
  auto alloc = [&](size_t bytes) {
    char* p = w + used;
    used += (bytes + 255) & ~(size_t)255;
    return p;
  };
  bf16*  h      = (bf16*)alloc((size_t)NN * HLD * 2);            // 60.8 MB
  bf16*  aggS   = (bf16*)alloc((size_t)MPAD * 320 * 2);          // 64.2 MB
  bf16*  B1n    = (bf16*)alloc((size_t)5 * 640 * 640 * 2);       // 4.1 MB
  bf16*  B2n    = (bf16*)alloc((size_t)5 * 384 * 1280 * 2);      // 4.9 MB
  float* b1p    = (float*)alloc(5 * 640 * 4);
  float* b2p    = (float*)alloc(5 * 384 * 4);
  int*   rowptr = (int*)alloc((NN + 4) * 4);
  int*   packed = (int*)alloc(NE * 4);
  float* stats  = (float*)alloc(768 * 4);
  float* coef   = (float*)alloc(2 * HLD * 4);

  // Overlays into aggS (disjoint lifetimes):
  int*   cnt    = (int*)aggS;           // CSR temps: dead before first k_agg
  int*   cursor = cnt + NN;
  int*   bsum   = cursor + NN;
  int*   bpre   = bsum + 512;
  float* pooled = (float*)aggS;         // head temps: after last GEMM1
  float* t1     = pooled + (size_t)NG * EMB;
  float* feats  = t1 + (size_t)NG * EMB;

  // h1 chunk buffer [CHUNK][608] bf16 from remaining workspace (512KB slack),
  // CHUNK multiple of 256.
  long long avail = (long long)ws_size - (long long)used - 524288;
  long long rows = avail / (608 * 2);
  if (rows > MPAD) rows = MPAD;
  if (rows < 256) rows = 256;
  int nch = (int)((NN + rows - 1) / rows);
  int CHUNK = ((NN + nch - 1) / nch + 255) & ~255;
  bf16* h1S = (bf16*)(w + used);

  // CSR build (temporaries live in aggS region)
  hipMemsetAsync(cnt, 0, NN * 4, stream);
  k_count<<<(NE + 255) / 256, 256, 0, stream>>>(ei + NE, cnt);
  k_bsum<<<NB_SC, 256, 0, stream>>>(cnt, bsum);
  k_bscan<<<1, 512, 0, stream>>>(bsum, bpre);
  k_expand<<<NB_SC, 256, 0, stream>>>(cnt, bpre, rowptr, cursor);
  k_fill<<<(NE + 255) / 256, 256, 0, stream>>>(ei, ea, cursor, packed);

  // zero aggS padding rows [NN, MPAD)
  hipMemsetAsync(aggS + (size_t)NN * 320, 0, (size_t)(MPAD - NN) * 320 * 2, stream);

  // weights prep
  k_prepw1<<<(5 * 640 * 640 + 255) / 256, 256, 0, stream>>>(W1, B1n);
  k_prepw2<<<(5 * 384 * 1280 + 255) / 256, 256, 0, stream>>>(W2, B2n);
  k_prepb<<<(5 * 640 + 5 * 384 + 255) / 256, 256, 0, stream>>>(b1, b2, b1p, b2p);

  // h0 (raw bf16)
  k_init<<<(NN * 76 + 255) / 256, 256, 0, stream>>>(
      x, (const float4*)atom_emb1, (const float4*)atom_emb2, h);

  for (int l = 0; l < NLAYERS; ++l) {
    const float* be1 = bond_emb1 + (size_t)l * 6 * EMB;
    const float* be2 = bond_emb2 + (size_t)l * 3 * EMB;
    if (l == 0)
      k_agg<0><<<NN / 4, 256, 0, stream>>>(h, rowptr, packed, be1, be2, coef, aggS);
    else
      k_agg<1><<<NN / 4, 256, 0, stream>>>(h, rowptr, packed, be1, be2, coef, aggS);

    hipMemsetAsync(stats, 0, 768 * 4, stream);
    for (int c0 = 0; c0 < NN; c0 += CHUNK) {
      int m = NN - c0 < CHUNK ? NN - c0 : CHUNK;
      int mt = (m + 255) / 256;
      // GEMM1: A=aggS hi (320), B=B1n (640, B_LO 320), NTILE=5
      k_mfma<5, 320, 640, 320, 1, 5><<<5 * mt, 512, 0, stream>>>(
          aggS + (size_t)c0 * 320, B1n + (size_t)l * 640 * 640,
          b1p + l * 640, h1S, nullptr, 0);
      // GEMM2: A=h1S (608), B=B2n (1280, B_LO 640), NTILE=3
      k_mfma<10, 608, 1280, 640, 2, 3><<<3 * mt, 512, 0, stream>>>(
          h1S, B2n + (size_t)l * 384 * 1280,
          b2p + l * 384, h + (size_t)c0 * HLD, stats, NN - c0);
    }
    k_bnfinal<<<1, 320, 0, stream>>>(stats, bn_scale + (size_t)l * EMB,
                                     bn_bias + (size_t)l * EMB, coef);
  }

  k_pool<<<NG, 256, 0, stream>>>(h, batch, coef, pooled);
  k_rowgemm<true><<<NG, 256, 0, stream>>>(pooled, pW1, pb1, t1);
  k_rowgemm<false><<<NG, 256, 0, stream>>>(t1, pW2, pb2, feats);
  k_norm<<<NG, 256, 0, stream>>>(feats);
  k_logits<<<dim3(32, 32), dim3(16, 16), 0, stream>>>(feats, out);
}

// Round 16
// 1980.888 us; speedup vs baseline: 1.0403x; 1.0403x over previous
//
#include <hip/hip_runtime.h>

#define EMB   300
#define EMB2  600
#define NLAYERS 5
#define NN    100000
#define NE    400000
#define NG    1024
#define BN_EPS 1e-5f
#define MPAD  100352            // 512*196 (covers 256- and 512-row tile overreads)
#define NB_SC 391               // ceil(NN/256)
#define HLD   304               // h row stride (bf16): 300 real + 4 pad

// h   : [NN][304] bf16, RAW (pre-BN) layer output; BN applied on read.
// aggS: [MPAD][320] bf16 hi-only (300 real + 20 zero cols)
// h1S : [CHUNK][608] bf16 (600 real + 8 zero)
// B1n : [L][640 n][640 k]  : k [0,320)=W1h (kk<300 real), [320,640)=W1l
// B2n : [L][320 n][1280 k] : k [0,640)=W2h (kk<600 real), [640,1280)=W2l
// All A K-windows are 64-aligned; A overreads pair with ZERO B rows.
// stats: sum at [0,384), sumsq at [384,768)

typedef __bf16 bf16;
typedef __attribute__((ext_vector_type(4))) __bf16 bf16x4;
typedef __attribute__((ext_vector_type(8))) __bf16 bf16x8;
typedef __attribute__((ext_vector_type(4))) float f32x4;

typedef __attribute__((address_space(3))) unsigned int lds_uint;
typedef __attribute__((address_space(1))) const unsigned int gbl_uint;

__device__ __forceinline__ void gld_lds16(const bf16* g, bf16* l) {
  // async 16B/lane HBM->LDS; LDS dest = wave-uniform base + lane*16
  __builtin_amdgcn_global_load_lds((gbl_uint*)g, (lds_uint*)l, 16, 0, 0);
}

// ---------------- CSR build ----------------
__global__ void k_count(const int* __restrict__ dst, int* __restrict__ cnt) {
  int e = blockIdx.x * 256 + threadIdx.x;
  if (e < NE) atomicAdd(&cnt[dst[e]], 1);
}

__global__ void k_bsum(const int* __restrict__ cnt, int* __restrict__ bsum) {
  __shared__ int red[256];
  int i = blockIdx.x * 256 + threadIdx.x;
  red[threadIdx.x] = (i < NN) ? cnt[i] : 0;
  __syncthreads();
  for (int off = 128; off; off >>= 1) {
    if (threadIdx.x < off) red[threadIdx.x] += red[threadIdx.x + off];
    __syncthreads();
  }
  if (!threadIdx.x) bsum[blockIdx.x] = red[0];
}

__global__ void k_bscan(const int* __restrict__ bsum, int* __restrict__ bpre) {
  __shared__ int s[512];
  int t = threadIdx.x;
  s[t] = (t < NB_SC) ? bsum[t] : 0;
  __syncthreads();
  for (int off = 1; off < 512; off <<= 1) {
    int v = (t >= off) ? s[t - off] : 0;
    __syncthreads();
    s[t] += v;
    __syncthreads();
  }
  if (t < NB_SC) bpre[t] = t ? s[t - 1] : 0;
}

__global__ void k_expand(const int* __restrict__ cnt, const int* __restrict__ bpre,
                         int* __restrict__ rowptr, int* __restrict__ cursor) {
  __shared__ int s[256];
  int t = threadIdx.x, i = blockIdx.x * 256 + t;
  int v = (i < NN) ? cnt[i] : 0;
  s[t] = v;
  __syncthreads();
  for (int off = 1; off < 256; off <<= 1) {
    int u = (t >= off) ? s[t - off] : 0;
    __syncthreads();
    s[t] += u;
    __syncthreads();
  }
  int excl = bpre[blockIdx.x] + s[t] - v;
  if (i < NN) { rowptr[i] = excl; cursor[i] = excl; }
  if (i == NN - 1) rowptr[NN] = excl + v;
}

__global__ void k_fill(const int* __restrict__ ei, const int* __restrict__ ea,
                       int* __restrict__ cursor, int* __restrict__ packed) {
  int e = blockIdx.x * 256 + threadIdx.x;
  if (e >= NE) return;
  int d = ei[NE + e];
  int s = ei[e];
  int comb = ea[2 * e] * 3 + ea[2 * e + 1];
  int pos = atomicAdd(&cursor[d], 1);
  packed[pos] = s | (comb << 20);
}

// ---------------- init h (bf16, raw) ----------------
__global__ void k_init(const int* __restrict__ x, const float4* __restrict__ ae1,
                       const float4* __restrict__ ae2, bf16* __restrict__ h) {
  int idx = blockIdx.x * 256 + threadIdx.x;
  if (idx >= NN * 76) return;
  int n = idx / 76, v = idx - n * 76;
  bf16x4 r4;
  if (v < 75) {
    int x0 = x[2 * n], x1 = x[2 * n + 1];
    float4 a = ae1[x0 * 75 + v], b = ae2[x1 * 75 + v];
    r4[0] = (bf16)(a.x + b.x); r4[1] = (bf16)(a.y + b.y);
    r4[2] = (bf16)(a.z + b.z); r4[3] = (bf16)(a.w + b.w);
  } else {
    r4[0] = r4[1] = r4[2] = r4[3] = (bf16)0.f;
  }
  *(bf16x4*)(h + (size_t)n * HLD + 4 * v) = r4;
}

// ---------------- weight/bias prep (split bf16, dup-free, N-major) ----------
__global__ void k_prepw1(const float* __restrict__ W1, bf16* __restrict__ B1n) {
  int idx = blockIdx.x * 256 + threadIdx.x;
  if (idx >= 5 * 640 * 640) return;
  int l = idx / (640 * 640), rem = idx - l * (640 * 640);
  int n = rem / 640, kp = rem - n * 640;
  int lo = kp >= 320;
  int kk = lo ? kp - 320 : kp;
  float w = (n < 600 && kk < 300) ? W1[(size_t)l * 300 * 600 + kk * 600 + n] : 0.f;
  bf16 hi = (bf16)w;
  B1n[idx] = lo ? (bf16)(w - (float)hi) : hi;
}

__global__ void k_prepw2(const float* __restrict__ W2, bf16* __restrict__ B2n) {
  int idx = blockIdx.x * 256 + threadIdx.x;
  if (idx >= 5 * 320 * 1280) return;
  int l = idx / (320 * 1280), rem = idx - l * (320 * 1280);
  int n = rem / 1280, kp = rem - n * 1280;
  int lo = kp >= 640;
  int kk = lo ? kp - 640 : kp;
  float w = (n < 300 && kk < 600) ? W2[(size_t)l * 600 * 300 + kk * 300 + n] : 0.f;
  bf16 hi = (bf16)w;
  B2n[idx] = lo ? (bf16)(w - (float)hi) : hi;
}

__global__ void k_prepb(const float* __restrict__ b1, const float* __restrict__ b2,
                        float* __restrict__ b1p, float* __restrict__ b2p) {
  int idx = blockIdx.x * 256 + threadIdx.x;
  if (idx < 5 * 640) {
    int l = idx / 640, n = idx - l * 640;
    b1p[idx] = (n < 600) ? b1[l * 600 + n] : 0.f;
  } else if (idx < 5 * 640 + 5 * 320) {
    int j = idx - 5 * 640;
    int l = j / 320, n = j - l * 320;
    b2p[j] = (n < 300) ? b2[l * 300 + n] : 0.f;
  }
}

// ---------------- aggregation (wave per node, bf16x8 vector gather) -----------
// r11 version (proven best).
template <int APPLY>
__global__ __launch_bounds__(256) void k_agg(
    const bf16* __restrict__ h, const int* __restrict__ rowptr,
    const int* __restrict__ packed, const float* __restrict__ be1,
    const float* __restrict__ be2, const float* __restrict__ coef,
    bf16* __restrict__ aggS) {
  __shared__ float tab[9 * HLD];            // 304-padded rows; cols >=300 zero
  for (int i = threadIdx.x; i < 9 * HLD; i += 256) {
    int cc = i / HLD, d = i - cc * HLD;
    tab[i] = (d < EMB)
                 ? be1[(cc / 3) * EMB + d] + be2[(cc - (cc / 3) * 3) * EMB + d]
                 : 0.f;
  }
  __syncthreads();
  const int ty = threadIdx.x >> 6, lane = threadIdx.x & 63;
  const int n = blockIdx.x * 4 + ty;
  const int c = 8 * lane;                   // this lane's chunk base col
  const bool act = lane < 38;               // chunks 0..37 = cols 0..303

  float a8[8], b8[8], acc[8];
  if (act) {
#pragma unroll
    for (int j = 0; j < 8; j++) {
      int d = c + j;
      a8[j] = APPLY ? coef[d] : 1.f;
      b8[j] = APPLY ? coef[HLD + d] : 0.f;
    }
    const bf16* hn = h + (size_t)n * HLD;
#pragma unroll
    for (int j = 0; j < 8; j++) {
      int d = c + j;
      float hv = (float)hn[d];
      if (APPLY) hv = fmaxf(fmaf(a8[j], hv, b8[j]), 0.f);
      acc[j] = hv + be1[4 * EMB + d] + be2[d];
    }
  }
  int e0 = rowptr[n], e1 = rowptr[n + 1];
  for (int e = e0; e < e1; ++e) {
    int pk = packed[e];
    const bf16* hr = h + (size_t)(pk & 0xFFFFF) * HLD;
    const float* tr = tab + (pk >> 20) * HLD;
    if (act) {
      bf16x8 v = *(const bf16x8*)(hr + c);
      f32x4 t0 = *(const f32x4*)(tr + c);
      f32x4 t1 = *(const f32x4*)(tr + c + 4);
#pragma unroll
      for (int j = 0; j < 8; j++) {
        float hv = (float)v[j];
        if (APPLY) hv = fmaxf(fmaf(a8[j], hv, b8[j]), 0.f);
        acc[j] += hv + (j < 4 ? t0[j] : t1[j - 4]);
      }
    }
  }
  bf16* row = aggS + (size_t)n * 320;
  if (lane < 40) {                          // chunks 38,39 = pad cols 304..319
    bf16x8 o;
#pragma unroll
    for (int j = 0; j < 8; j++)
      o[j] = (act && c + j < EMB) ? (bf16)acc[j] : (bf16)0.f;
    *(bf16x8*)(row + c) = o;
  }
}

// ---------------- MFMA GEMM (A-stationary dual-section, templated wave grid) --
// 512 threads = 8 waves arranged (8/WC) wr x WC wc; block = (512/WC) rows x
// (WC*64) cols. WC=2 = 256x128 (GEMM1); WC=1 = 512x64 (GEMM2, N=320 only —
// no dead columns). Single-buffer LDS, 2 barriers per K-window (the r11
// schedule; dbuf/counted-vmcnt/NLIM variants all regressed or were neutral).
// Per-accumulator MFMA K-order unchanged -> numerically identical.
// XOR bank-swizzle via PRE-SWIZZLED global source chunk (l&7)^(l>>3).
// MODE 1: C = h1S (ld 608): relu, write gcol<608.
// MODE 2: C = h raw bf16 (ld 304), gcol<304 && grow<row_limit; fused BN stats.
template <int K_SECT, int LDA, int LDB, int B_LO, int MODE, int NTILE, int WC>
__global__ __launch_bounds__(512) void k_mfma(
    const bf16* __restrict__ A,
    const bf16* __restrict__ Bn,
    const float* __restrict__ bias,
    bf16* __restrict__ C, float* __restrict__ stats, int row_limit) {
  constexpr int RB = 512 / WC;             // block rows
  constexpr int NB = WC * 64;              // block cols
  __shared__ __align__(16) bf16 As[RB * 64];
  __shared__ __align__(16) bf16 Bs0[NB * 64];
  __shared__ __align__(16) bf16 Bs1[NB * 64];
  const int t = threadIdx.x, lane = t & 63, wid = t >> 6;
  const int wr = wid / WC, wc = wid % WC;

  // bijective XCD swizzle (m204)
  const int nwg = (int)gridDim.x;
  const int q = nwg >> 3, r = nwg & 7;
  const int xcd = blockIdx.x & 7, slot = blockIdx.x >> 3;
  const int lin = (xcd < r ? xcd * (q + 1) : r * (q + 1) + (xcd - r) * q) + slot;
  const int row0 = (lin / NTILE) * RB, n0 = (lin % NTILE) * NB;

  // per-lane pre-swizzled source chunk + row-within-instruction
  const int csw = (lane & 7) ^ (lane >> 3);       // global 8-elem chunk index
  const int r8  = lane >> 3;                       // row within 8-row inst

  auto stage = [&](int kt) {
    int kbase = kt * 64;
    const bf16* ga = A  + (size_t)(row0 + wid * (RB / 8) + r8) * LDA + kbase + csw * 8;
    const bf16* gb = Bn + (size_t)(n0  + wid * (NB / 8) + r8) * LDB + kbase + csw * 8;
#pragma unroll
    for (int i = 0; i < RB / 64; i++)
      gld_lds16(ga + (size_t)(i * 8) * LDA, &As[(wid * (RB / 8) + i * 8) * 64]);
#pragma unroll
    for (int i = 0; i < NB / 64; i++) {
      gld_lds16(gb + (size_t)(i * 8) * LDB,        &Bs0[(wid * (NB / 8) + i * 8) * 64]);
      gld_lds16(gb + (size_t)(i * 8) * LDB + B_LO, &Bs1[(wid * (NB / 8) + i * 8) * 64]);
    }
  };

  f32x4 acc[4][4] = {};
#pragma unroll 2
  for (int kt = 0; kt < K_SECT; kt++) {
    stage(kt);
    __syncthreads();               // drains vmcnt: staged tiles visible
#pragma unroll
    for (int kk = 0; kk < 2; kk++) {
      bf16x8 af[4], b0[4], b1[4];
#pragma unroll
      for (int mf = 0; mf < 4; mf++) {
        int rr = wr * 64 + mf * 16 + (lane & 15);
        int cc = (kk * 4 + (lane >> 4)) ^ (rr & 7);
        af[mf] = *(const bf16x8*)((const char*)&As[0] + rr * 128 + (cc << 4));
      }
#pragma unroll
      for (int nf = 0; nf < 4; nf++) {
        int n = wc * 64 + nf * 16 + (lane & 15);
        int cc = (kk * 4 + (lane >> 4)) ^ (n & 7);
        b0[nf] = *(const bf16x8*)((const char*)&Bs0[0] + n * 128 + (cc << 4));
        b1[nf] = *(const bf16x8*)((const char*)&Bs1[0] + n * 128 + (cc << 4));
      }
#pragma unroll
      for (int mf = 0; mf < 4; mf++)
#pragma unroll
        for (int nf = 0; nf < 4; nf++) {
          acc[mf][nf] = __builtin_amdgcn_mfma_f32_16x16x32_bf16(
              af[mf], b0[nf], acc[mf][nf], 0, 0, 0);
          acc[mf][nf] = __builtin_amdgcn_mfma_f32_16x16x32_bf16(
              af[mf], b1[nf], acc[mf][nf], 0, 0, 0);
        }
    }
    __syncthreads();               // all reads done before next stage overwrites
  }

  const int rq = (lane >> 4) << 2;   // 0,4,8,12
  const int cl = lane & 15;
#pragma unroll
  for (int nf = 0; nf < 4; nf++) {
    const int gcol = n0 + wc * 64 + nf * 16 + cl;
    float s = 0.f, qq = 0.f;
#pragma unroll
    for (int mf = 0; mf < 4; mf++)
#pragma unroll
      for (int rr = 0; rr < 4; rr++) {
        int grow = row0 + wr * 64 + mf * 16 + rq + rr;
        float v = acc[mf][nf][rr] + bias[gcol];
        if (MODE == 1) {
          if (gcol < 608) C[(size_t)grow * 608 + gcol] = (bf16)fmaxf(v, 0.f);
        } else {
          if (grow < row_limit) {
            if (gcol < HLD) C[(size_t)grow * HLD + gcol] = (bf16)v;
            s += v; qq += v * v;
          }
        }
      }
    if (MODE == 2) {
      s  += __shfl_down(s, 32);  s  += __shfl_down(s, 16);
      qq += __shfl_down(qq, 32); qq += __shfl_down(qq, 16);
      if (lane < 16 && gcol < EMB) {
        atomicAdd(&stats[gcol], s);
        atomicAdd(&stats[384 + gcol], qq);
      }
    }
  }
}

// ---------------- BN coef from fused stats ----------------
__global__ void k_bnfinal(const float* __restrict__ stats, const float* __restrict__ sc,
                          const float* __restrict__ bi, float* __restrict__ coef) {
  int c = threadIdx.x;
  if (c >= HLD) return;
  if (c < EMB) {
    float mean = stats[c] * (1.0f / NN);
    float var  = stats[384 + c] * (1.0f / NN) - mean * mean;
    float inv  = rsqrtf(var + BN_EPS);
    float a = inv * sc[c];
    coef[c] = a;
    coef[HLD + c] = bi[c] - mean * a;
  } else {
    coef[c] = 0.f;
    coef[HLD + c] = 0.f;
  }
}

// ---------------- pooling (applies final layer's BN, no relu) ----------------
__device__ __forceinline__ int lowerb(const int* a, int n, int v) {
  int lo = 0, hi = n;
  while (lo < hi) { int mid = (lo + hi) >> 1; if (a[mid] < v) lo = mid + 1; else hi = mid; }
  return lo;
}

__global__ void k_pool(const bf16* __restrict__ h, const int* __restrict__ batch,
                       const float* __restrict__ coef, float* __restrict__ pooled) {
  int g = blockIdx.x;
  __shared__ int se[2];
  if (threadIdx.x == 0) { se[0] = lowerb(batch, NN, g); se[1] = lowerb(batch, NN, g + 1); }
  __syncthreads();
  int start = se[0], end = se[1];
  for (int c = threadIdx.x; c < EMB; c += 256) {
    float s = 0.f;
    for (int r = start; r < end; ++r) s += (float)h[(size_t)r * HLD + c];
    float outv = 0.f;
    if (end > start) {
      float m = s / (float)(end - start);
      outv = fmaf(coef[c], m, coef[HLD + c]);
    }
    pooled[(size_t)g * EMB + c] = outv;
  }
}

// ---------------- projection head ----------------
template <bool RELU>
__global__ void k_rowgemm(const float* __restrict__ X, const float* __restrict__ W,
                          const float* __restrict__ bias, float* __restrict__ Y) {
  int g = blockIdx.x;
  __shared__ float row[EMB];
  for (int i = threadIdx.x; i < EMB; i += 256) row[i] = X[(size_t)g * EMB + i];
  __syncthreads();
  for (int c = threadIdx.x; c < EMB; c += 256) {
    float acc = bias[c];
    for (int k = 0; k < EMB; k++) acc += row[k] * W[(size_t)k * EMB + c];
    if (RELU) acc = fmaxf(acc, 0.f);
    Y[(size_t)g * EMB + c] = acc;
  }
}

__global__ void k_norm(float* __restrict__ p) {
  int g = blockIdx.x;
  __shared__ float red[256];
  float s = 0.f;
  for (int c = threadIdx.x; c < EMB; c += 256) { float v = p[(size_t)g * EMB + c]; s += v * v; }
  red[threadIdx.x] = s; __syncthreads();
  for (int off = 128; off > 0; off >>= 1) {
    if (threadIdx.x < off) red[threadIdx.x] += red[threadIdx.x + off];
    __syncthreads();
  }
  float inv = 1.0f / fmaxf(sqrtf(red[0]), 1e-12f);
  for (int c = threadIdx.x; c < EMB; c += 256) p[(size_t)g * EMB + c] *= inv;
}

__global__ __launch_bounds__(256) void k_logits(const float* __restrict__ feats,
                                                float* __restrict__ out) {
  __shared__ float SA[16 * EMB];
  __shared__ float SB[16 * EMB];
  int t = threadIdx.y * 16 + threadIdx.x;
  int i0 = blockIdx.y * 16, j0 = blockIdx.x * 16;
  for (int idx = t; idx < 16 * EMB; idx += 256) {
    int r = idx / EMB, c = idx - r * EMB;
    SA[idx] = feats[(size_t)(i0 + r) * EMB + c];
    SB[idx] = feats[(size_t)(512 + j0 + r) * EMB + c];
  }
  __syncthreads();
  float acc = 0.f;
  const float* a = &SA[threadIdx.y * EMB];
  const float* b = &SB[threadIdx.x * EMB];
  for (int k = 0; k < EMB; k++) acc += a[k] * b[k];
  out[(size_t)(i0 + threadIdx.y) * 512 + j0 + threadIdx.x] = acc / 0.04f;
}

// ---------------- host ----------------
extern "C" void kernel_launch(void* const* d_in, const int* in_sizes, int n_in,
                              void* d_out, int out_size, void* d_ws, size_t ws_size,
                              hipStream_t stream) {
  const int*   x         = (const int*)d_in[0];
  const int*   ei        = (const int*)d_in[1];
  const int*   ea        = (const int*)d_in[2];
  const int*   batch     = (const int*)d_in[3];
  const float* atom_emb1 = (const float*)d_in[4];
  const float* atom_emb2 = (const float*)d_in[5];
  const float* bond_emb1 = (const float*)d_in[6];
  const float* bond_emb2 = (const float*)d_in[7];
  const float* W1        = (const float*)d_in[8];
  const float* b1        = (const float*)d_in[9];
  const float* W2        = (const float*)d_in[10];
  const float* b2        = (const float*)d_in[11];
  const float* bn_scale  = (const float*)d_in[12];
  const float* bn_bias   = (const float*)d_in[13];
  const float* pW1       = (const float*)d_in[14];
  const float* pb1       = (const float*)d_in[15];
  const float* pW2       = (const float*)d_in[16];
  const float* pb2       = (const float*)d_in[17];
  float* out = (float*)d_out;

  char* w = (char*)d_ws;
  size_t used = 0;
  auto alloc = [&](size_t bytes) {
    char* p = w + used;
    used += (bytes + 255) & ~(size_t)255;
    return p;
  };
  bf16*  h      = (bf16*)alloc((size_t)NN * HLD * 2);            // 60.8 MB
  bf16*  aggS   = (bf16*)alloc((size_t)MPAD * 320 * 2);          // 64.2 MB
  bf16*  B1n    = (bf16*)alloc((size_t)5 * 640 * 640 * 2);       // 4.1 MB
  bf16*  B2n    = (bf16*)alloc((size_t)5 * 320 * 1280 * 2);      // 4.1 MB
  float* b1p    = (float*)alloc(5 * 640 * 4);
  float* b2p    = (float*)alloc(5 * 320 * 4);
  int*   rowptr = (int*)alloc((NN + 4) * 4);
  int*   packed = (int*)alloc(NE * 4);
  float* stats  = (float*)alloc(768 * 4);
  float* coef   = (float*)alloc(2 * HLD * 4);

  // Overlays into aggS (disjoint lifetimes):
  int*   cnt    = (int*)aggS;           // CSR temps: dead before first k_agg
  int*   cursor = cnt + NN;
  int*   bsum   = cursor + NN;
  int*   bpre   = bsum + 512;
  float* pooled = (float*)aggS;         // head temps: after last GEMM1
  float* t1     = pooled + (size_t)NG * EMB;
  float* feats  = t1 + (size_t)NG * EMB;

  // h1 chunk buffer [CHUNK][608] bf16 from remaining workspace (512KB slack),
  // CHUNK multiple of 512 (lcm of both M-tile heights).
  long long avail = (long long)ws_size - (long long)used - 524288;
  long long rows = avail / (608 * 2);
  if (rows > MPAD) rows = MPAD;
  if (rows < 512) rows = 512;
  int nch = (int)((NN + rows - 1) / rows);
  int CHUNK = ((NN + nch - 1) / nch + 511) & ~511;
  bf16* h1S = (bf16*)(w + used);

  // CSR build (temporaries live in aggS region)
  hipMemsetAsync(cnt, 0, NN * 4, stream);
  k_count<<<(NE + 255) / 256, 256, 0, stream>>>(ei + NE, cnt);
  k_bsum<<<NB_SC, 256, 0, stream>>>(cnt, bsum);
  k_bscan<<<1, 512, 0, stream>>>(bsum, bpre);
  k_expand<<<NB_SC, 256, 0, stream>>>(cnt, bpre, rowptr, cursor);
  k_fill<<<(NE + 255) / 256, 256, 0, stream>>>(ei, ea, cursor, packed);

  // zero aggS padding rows [NN, MPAD)
  hipMemsetAsync(aggS + (size_t)NN * 320, 0, (size_t)(MPAD - NN) * 320 * 2, stream);

  // weights prep
  k_prepw1<<<(5 * 640 * 640 + 255) / 256, 256, 0, stream>>>(W1, B1n);
  k_prepw2<<<(5 * 320 * 1280 + 255) / 256, 256, 0, stream>>>(W2, B2n);
  k_prepb<<<(5 * 640 + 5 * 320 + 255) / 256, 256, 0, stream>>>(b1, b2, b1p, b2p);

  // h0 (raw bf16)
  k_init<<<(NN * 76 + 255) / 256, 256, 0, stream>>>(
      x, (const float4*)atom_emb1, (const float4*)atom_emb2, h);

  for (int l = 0; l < NLAYERS; ++l) {
    const float* be1 = bond_emb1 + (size_t)l * 6 * EMB;
    const float* be2 = bond_emb2 + (size_t)l * 3 * EMB;
    if (l == 0)
      k_agg<0><<<NN / 4, 256, 0, stream>>>(h, rowptr, packed, be1, be2, coef, aggS);
    else
      k_agg<1><<<NN / 4, 256, 0, stream>>>(h, rowptr, packed, be1, be2, coef, aggS);

    hipMemsetAsync(stats, 0, 768 * 4, stream);
    for (int c0 = 0; c0 < NN; c0 += CHUNK) {
      int m = NN - c0 < CHUNK ? NN - c0 : CHUNK;
      int mt1 = (m + 255) / 256;
      int mt2 = (m + 511) / 512;
      // GEMM1: WC=2 (256x128). A=aggS hi (320), B=B1n (640, B_LO 320)
      k_mfma<5, 320, 640, 320, 1, 5, 2><<<5 * mt1, 512, 0, stream>>>(
          aggS + (size_t)c0 * 320, B1n + (size_t)l * 640 * 640,
          b1p + l * 640, h1S, nullptr, 0);
      // GEMM2: WC=1 (512x64, N=320 only). A=h1S (608), B=B2n (1280, B_LO 640)
      k_mfma<10, 608, 1280, 640, 2, 5, 1><<<5 * mt2, 512, 0, stream>>>(
          h1S, B2n + (size_t)l * 320 * 1280,
          b2p + l * 320, h + (size_t)c0 * HLD, stats, NN - c0);
    }
    k_bnfinal<<<1, 320, 0, stream>>>(stats, bn_scale + (size_t)l * EMB,
                                     bn_bias + (size_t)l * EMB, coef);
  }

  k_pool<<<NG, 256, 0, stream>>>(h, batch, coef, pooled);
  k_rowgemm<true><<<NG, 256, 0, stream>>>(pooled, pW1, pb1, t1);
  k_rowgemm<false><<<NG, 256, 0, stream>>>(t1, pW2, pb2, feats);
  k_norm<<<NG, 256, 0, stream>>>(feats);
  k_logits<<<dim3(32, 32), dim3(16, 16), 0, stream>>>(feats, out);
}